// Round 1
// baseline (249.222 us; speedup 1.0000x reference)
//
#include <hip/hip_runtime.h>
#include <stdint.h>

typedef float f32x4 __attribute__((ext_vector_type(4)));
typedef short s16x8 __attribute__((ext_vector_type(8)));
typedef unsigned short u16;

#define LOG2E 1.44269504088896340736f

__device__ __forceinline__ u16 f2bf(float f) {
    union { float f; uint32_t u; } v; v.f = f;
    uint32_t r = v.u + 0x7FFFu + ((v.u >> 16) & 1u);
    return (u16)(r >> 16);
}

// ---------------------------------------------------------------------------
// Kernel 1: QKV projection (1x1 convs).
//   x: [B=4][C=64][4096] fp32
//   QT: [B][4096][8]  bf16  (q * LOG2E folded in, so attention can use exp2)
//   KT: [B][4096][8]  bf16
//   V : [B][64][4096] bf16
// 256 blocks x 256 threads. Block = 64 pixels of one batch. Wave w computes
// V channels [16w,16w+16); wave 0 also Q, wave 1 also K. Weights are read via
// wave-uniform indices -> scalar loads (s_load), no LDS needed.
// ---------------------------------------------------------------------------
__global__ __launch_bounds__(256) void qkv_kernel(
    const float* __restrict__ x,
    const float* __restrict__ Wq, const float* __restrict__ bq,
    const float* __restrict__ Wk, const float* __restrict__ bk,
    const float* __restrict__ Wv, const float* __restrict__ bv,
    u16* __restrict__ QT, u16* __restrict__ KT, u16* __restrict__ Vg)
{
    const int tid  = threadIdx.x;
    const int lane = tid & 63;
    const int wave = tid >> 6;
    const int blk  = blockIdx.x;       // 256 blocks
    const int b    = blk >> 6;         // batch
    const int j    = ((blk & 63) << 6) + lane;  // pixel index in [0,4096)

    const float* xb = x + (size_t)b * 64 * 4096 + j;
    float xv[64];
#pragma unroll
    for (int c = 0; c < 64; ++c) xv[c] = xb[(size_t)c * 4096];

    // V channels for this wave
    const int c0 = wave * 16;
    for (int co = 0; co < 16; ++co) {
        const int co_g = c0 + co;
        const float* wrow = Wv + co_g * 64;   // wave-uniform -> s_load
        float acc = bv[co_g];
#pragma unroll
        for (int cin = 0; cin < 64; ++cin) acc += wrow[cin] * xv[cin];
        Vg[((size_t)(b * 64 + co_g)) * 4096 + j] = f2bf(acc);
    }

    if (wave == 0) {
        union { u16 u[8]; uint4 v; } q;
#pragma unroll
        for (int d = 0; d < 8; ++d) {
            const float* wrow = Wq + d * 64;
            float acc = bq[d];
#pragma unroll
            for (int cin = 0; cin < 64; ++cin) acc += wrow[cin] * xv[cin];
            q.u[d] = f2bf(acc * LOG2E);   // fold log2(e) into Q
        }
        *(uint4*)(QT + ((size_t)b * 4096 + j) * 8) = q.v;
    } else if (wave == 1) {
        union { u16 u[8]; uint4 v; } k;
#pragma unroll
        for (int d = 0; d < 8; ++d) {
            const float* wrow = Wk + d * 64;
            float acc = bk[d];
#pragma unroll
            for (int cin = 0; cin < 64; ++cin) acc += wrow[cin] * xv[cin];
            k.u[d] = f2bf(acc);
        }
        *(uint4*)(KT + ((size_t)b * 4096 + j) * 8) = k.v;
    }
}

// ---------------------------------------------------------------------------
// Kernel 2: flash attention, no-max softmax (logits bounded ~|40| << 88).
// 256 blocks (b = blk>>6, i0 = (blk&63)*64) x 4 waves. Wave w owns queries
// [i0+16w, i0+16w+16) and loops over ALL 4096 keys in tiles of 64.
// Per j-tile:
//   S (16x64) via 4x mfma_f32_16x16x32_bf16, K=8 zero-padded (quads 1-3 = 0)
//   P = exp2(S) in C-layout regs; row-sums accumulated per (quad,reg)
//   P -> LDS (bf16, per-wave region, row stride 72) -> A-frags (ds_read_b128)
//   O^T (16x64) += P * V^T via 8x mfma; V B-frags read directly from global
// Epilogue: row-sum shuffle-reduce over 16 lanes, O /= l, out = g*O + x.
// ---------------------------------------------------------------------------
#define P_STRIDE 72   // bf16 elems; 144 B row stride, 16B-aligned

__global__ __launch_bounds__(256) void attn_kernel(
    const u16* __restrict__ QT, const u16* __restrict__ KT,
    const u16* __restrict__ Vg, const float* __restrict__ x,
    const float* __restrict__ gamma, float* __restrict__ out)
{
    __shared__ u16 p_lds[4][16 * P_STRIDE];   // 9216 B

    const int tid  = threadIdx.x;
    const int lane = tid & 63;
    const int wave = tid >> 6;
    const int col  = lane & 15;   // n-index within mfma tile
    const int quad = lane >> 4;   // 0..3
    const int blk  = blockIdx.x;
    const int b    = blk >> 6;
    const int i0   = (blk & 63) << 6;
    const int iw   = i0 + wave * 16;          // this wave's first query

    const u16* KTb = KT + (size_t)b * 4096 * 8;
    const u16* Vb  = Vg + (size_t)b * 64 * 4096;

    // Q A-fragment: A[m=col][k=quad*8+t]; only quad 0 holds real data (d=0..7)
    s16x8 aq = {0,0,0,0,0,0,0,0};
    if (quad == 0)
        aq = *(const s16x8*)(QT + ((size_t)b * 4096 + iw + col) * 8);

    f32x4 o[4];
#pragma unroll
    for (int nt = 0; nt < 4; ++nt) o[nt] = (f32x4){0.f, 0.f, 0.f, 0.f};
    float lsum[4] = {0.f, 0.f, 0.f, 0.f};

    u16* pl = &p_lds[wave][0];
    const f32x4 zero = {0.f, 0.f, 0.f, 0.f};

    for (int j0 = 0; j0 < 4096; j0 += 64) {
        // ---- S = Q^T K for 16 queries x 64 keys ----
        f32x4 s[4];
#pragma unroll
        for (int nt = 0; nt < 4; ++nt) {
            s16x8 bk = {0,0,0,0,0,0,0,0};
            if (quad == 0)
                bk = *(const s16x8*)(KTb + (size_t)(j0 + nt * 16 + col) * 8);
            s[nt] = __builtin_amdgcn_mfma_f32_16x16x32_bf16(aq, bk, zero, 0, 0, 0);
        }
        // ---- P = exp2(S) (log2e folded into Q); accumulate row sums; stash P ----
#pragma unroll
        for (int nt = 0; nt < 4; ++nt) {
#pragma unroll
            for (int r = 0; r < 4; ++r) {
                float p = exp2f(s[nt][r]);
                lsum[r] += p;
                // P row = quad*4+r (query), col = nt*16+col (key within tile)
                pl[(quad * 4 + r) * P_STRIDE + nt * 16 + col] = f2bf(p);
            }
        }
        __syncthreads();   // v1: bulletproof intra-wave write->read ordering

        // ---- A-frags of P: A[m=col][k = kst*32 + quad*8 + t] ----
        const s16x8 ap0 = *(const s16x8*)(pl + col * P_STRIDE + quad * 8);
        const s16x8 ap1 = *(const s16x8*)(pl + col * P_STRIDE + 32 + quad * 8);

        // ---- O^T += P * V^T ; B[k=j][n=c] = V[c][j0+k], direct from global ----
#pragma unroll
        for (int nt = 0; nt < 4; ++nt) {
            const u16* vp = Vb + (size_t)(nt * 16 + col) * 4096 + j0 + quad * 8;
            s16x8 bv0 = *(const s16x8*)(vp);
            s16x8 bv1 = *(const s16x8*)(vp + 32);
            o[nt] = __builtin_amdgcn_mfma_f32_16x16x32_bf16(ap0, bv0, o[nt], 0, 0, 0);
            o[nt] = __builtin_amdgcn_mfma_f32_16x16x32_bf16(ap1, bv1, o[nt], 0, 0, 0);
        }
        __syncthreads();   // protect p_lds WAR for next tile
    }

    // ---- finalize: reduce row sums over the 16 col-lanes of each quad ----
#pragma unroll
    for (int r = 0; r < 4; ++r) {
        float v = lsum[r];
        v += __shfl_xor(v, 1, 64);
        v += __shfl_xor(v, 2, 64);
        v += __shfl_xor(v, 4, 64);
        v += __shfl_xor(v, 8, 64);
        lsum[r] = 1.0f / v;
    }
    const float g = gamma[0];
#pragma unroll
    for (int nt = 0; nt < 4; ++nt) {
        const int c = nt * 16 + col;
#pragma unroll
        for (int r = 0; r < 4; ++r) {
            const int i = iw + quad * 4 + r;
            const size_t idx = ((size_t)(b * 64 + c)) * 4096 + i;
            out[idx] = g * (o[nt][r] * lsum[r]) + x[idx];
        }
    }
}

// ---------------------------------------------------------------------------
extern "C" void kernel_launch(void* const* d_in, const int* in_sizes, int n_in,
                              void* d_out, int out_size, void* d_ws, size_t ws_size,
                              hipStream_t stream)
{
    const float* x     = (const float*)d_in[0];
    const float* Wq    = (const float*)d_in[1];
    const float* bq    = (const float*)d_in[2];
    const float* Wk    = (const float*)d_in[3];
    const float* bk    = (const float*)d_in[4];
    const float* Wv    = (const float*)d_in[5];
    const float* bv    = (const float*)d_in[6];
    const float* gamma = (const float*)d_in[7];

    u16* QT = (u16*)d_ws;                 // [4][4096][8] bf16
    u16* KT = QT + (size_t)4 * 4096 * 8;  // [4][4096][8] bf16
    u16* Vg = KT + (size_t)4 * 4096 * 8;  // [4][64][4096] bf16

    qkv_kernel<<<256, 256, 0, stream>>>(x, Wq, bq, Wk, bk, Wv, bv, QT, KT, Vg);
    attn_kernel<<<256, 256, 0, stream>>>(QT, KT, Vg, x, gamma, (float*)d_out);
}

// Round 2
// 160.054 us; speedup vs baseline: 1.5571x; 1.5571x over previous
//
#include <hip/hip_runtime.h>
#include <stdint.h>

typedef float f32x4 __attribute__((ext_vector_type(4)));
typedef short s16x8 __attribute__((ext_vector_type(8)));
typedef unsigned short u16;

#define LOG2E 1.44269504088896340736f

#if __has_builtin(__builtin_amdgcn_exp2f)
#define EXP2F __builtin_amdgcn_exp2f
#else
#define EXP2F exp2f
#endif

__device__ __forceinline__ u16 f2bf(float f) {
    union { float f; uint32_t u; } v; v.f = f;
    uint32_t r = v.u + 0x7FFFu + ((v.u >> 16) & 1u);
    return (u16)(r >> 16);
}

// ---------------------------------------------------------------------------
// Kernel 1: QKV projection (1x1 convs).
//   x: [B=4][C=64][4096] fp32
//   QT: [B][4096][8]  bf16  (q * LOG2E folded in)
//   KT: [B][4096][8]  bf16
//   V : [B][64][4096] bf16
// 1024 blocks x 256 threads: blk -> (b, j-tile of 64 px, cgroup of 16 ch).
// Thread = one pixel; wave computes 4 V channels (row index readfirstlane'd
// so weight reads are s_loads, NOT per-lane broadcast vector loads).
// cgroup 0: wave0 also computes Q (8 rows), wave1 also K.
// ---------------------------------------------------------------------------
__global__ __launch_bounds__(256) void qkv_kernel(
    const float* __restrict__ x,
    const float* __restrict__ Wq, const float* __restrict__ bq,
    const float* __restrict__ Wk, const float* __restrict__ bk,
    const float* __restrict__ Wv, const float* __restrict__ bv,
    u16* __restrict__ QT, u16* __restrict__ KT, u16* __restrict__ Vg)
{
    const int tid  = threadIdx.x;
    const int lane = tid & 63;
    const int wave = tid >> 6;
    const int blk  = blockIdx.x;          // 1024 blocks
    const int b    = blk >> 8;            // batch
    const int sub  = blk & 255;
    const int jt   = sub >> 2;            // 64 j-tiles
    const int cg   = sub & 3;             // 4 channel groups of 16
    const int j    = (jt << 6) + lane;

    const float* xb = x + (size_t)b * 64 * 4096 + j;
    float xv[64];
#pragma unroll
    for (int c = 0; c < 64; ++c) xv[c] = xb[(size_t)c * 4096];

    // 4 V channels per thread; row index forced to SGPR -> s_load weights
#pragma unroll
    for (int co = 0; co < 4; ++co) {
        const int row = __builtin_amdgcn_readfirstlane(cg * 16 + wave * 4 + co);
        const float* wrow = Wv + row * 64;
        float acc = bv[row];
#pragma unroll
        for (int cin = 0; cin < 64; ++cin) acc += wrow[cin] * xv[cin];
        Vg[((size_t)(b * 64 + row)) * 4096 + j] = f2bf(acc);
    }

    if (cg == 0) {
        if (wave == 0) {
            union { u16 u[8]; uint4 v; } q;
#pragma unroll
            for (int d = 0; d < 8; ++d) {
                const float* wrow = Wq + d * 64;
                float acc = bq[d];
#pragma unroll
                for (int cin = 0; cin < 64; ++cin) acc += wrow[cin] * xv[cin];
                q.u[d] = f2bf(acc * LOG2E);
            }
            *(uint4*)(QT + ((size_t)b * 4096 + j) * 8) = q.v;
        } else if (wave == 1) {
            union { u16 u[8]; uint4 v; } k;
#pragma unroll
            for (int d = 0; d < 8; ++d) {
                const float* wrow = Wk + d * 64;
                float acc = bk[d];
#pragma unroll
                for (int cin = 0; cin < 64; ++cin) acc += wrow[cin] * xv[cin];
                k.u[d] = f2bf(acc);
            }
            *(uint4*)(KT + ((size_t)b * 4096 + j) * 8) = k.v;
        }
    }
}

// ---------------------------------------------------------------------------
// Kernel 2: flash attention, no-max softmax, split-K in-block.
// 256 blocks x 1024 threads (16 waves). blk -> (b, i-tile of 64 queries).
// wave w: qgroup qg=w&3 (16 queries), split sp=w>>2 (keys [sp*1024,+1024)).
// K-loop has NO barriers: P round-trips a per-wave-private LDS slice with
// an intra-wave s_waitcnt lgkmcnt(0) only. After the loop, one barrier;
// splits 1..3 park O/l partials in LDS; split 0 sums (partials of the no-max
// softmax combine additively), divides, writes out = g*O + x.
// ---------------------------------------------------------------------------
#define P_STRIDE 72   // bf16 elems; 144B rows, 16B-aligned for ds_read_b128
#define OX_STRIDE 68  // fp32 elems; breaks 4-quad bank aliasing (2-way only)

__global__ __launch_bounds__(1024, 4) void attn_kernel(
    const u16* __restrict__ QT, const u16* __restrict__ KT,
    const u16* __restrict__ Vg, const float* __restrict__ x,
    const float* __restrict__ gamma, float* __restrict__ out)
{
    __shared__ u16   p_lds[16][16 * P_STRIDE];   // 36864 B
    __shared__ float Ox[12][16 * OX_STRIDE];     // 52224 B
    __shared__ float Lx[12 * 16];                //   768 B

    const int tid  = threadIdx.x;
    const int lane = tid & 63;
    const int wave = tid >> 6;
    const int col  = lane & 15;
    const int quad = lane >> 4;
    const int qg   = wave & 3;          // query group
    const int sp   = wave >> 2;         // key split
    const int blk  = blockIdx.x;
    const int b    = blk >> 6;
    const int i0   = (blk & 63) << 6;
    const int iw   = i0 + qg * 16;      // this wave's first query

    const u16* KTb = KT + (size_t)b * 4096 * 8;
    const u16* Vb  = Vg + (size_t)b * 64 * 4096;

    // Q A-fragment: A[m=col][k=quad*8+t]; only quad 0 holds real data
    s16x8 aq = {0,0,0,0,0,0,0,0};
    if (quad == 0)
        aq = *(const s16x8*)(QT + ((size_t)b * 4096 + iw + col) * 8);

    f32x4 o[4];
#pragma unroll
    for (int nt = 0; nt < 4; ++nt) o[nt] = (f32x4){0.f, 0.f, 0.f, 0.f};
    float lsum[4] = {0.f, 0.f, 0.f, 0.f};

    u16* pl = &p_lds[wave][0];
    const f32x4 zero = {0.f, 0.f, 0.f, 0.f};

    const int jbeg = sp << 10;          // sp*1024
    const int jend = jbeg + 1024;
    for (int j0 = jbeg; j0 < jend; j0 += 64) {
        // ---- S = Q K^T : 16 queries x 64 keys ----
        f32x4 s[4];
#pragma unroll
        for (int nt = 0; nt < 4; ++nt) {
            s16x8 bk = {0,0,0,0,0,0,0,0};
            if (quad == 0)
                bk = *(const s16x8*)(KTb + (size_t)(j0 + nt * 16 + col) * 8);
            s[nt] = __builtin_amdgcn_mfma_f32_16x16x32_bf16(aq, bk, zero, 0, 0, 0);
        }
        // ---- P = exp2(S); row sums; stash P in this wave's LDS slice ----
#pragma unroll
        for (int nt = 0; nt < 4; ++nt) {
#pragma unroll
            for (int r = 0; r < 4; ++r) {
                float p = EXP2F(s[nt][r]);
                lsum[r] += p;
                pl[(quad * 4 + r) * P_STRIDE + nt * 16 + col] = f2bf(p);
            }
        }
        // intra-wave only: own writes -> own reads (DS completes in order)
        asm volatile("s_waitcnt lgkmcnt(0)" ::: "memory");

        // ---- P A-frags: A[m=col][k = kst*32 + quad*8 + t] ----
        const s16x8 ap0 = *(const s16x8*)(pl + col * P_STRIDE + quad * 8);
        const s16x8 ap1 = *(const s16x8*)(pl + col * P_STRIDE + 32 + quad * 8);

        // ---- O^T += P V^T ; B[k=j][n=c] = V[c][j0+k] straight from global ----
#pragma unroll
        for (int nt = 0; nt < 4; ++nt) {
            const u16* vp = Vb + (size_t)(nt * 16 + col) * 4096 + j0 + quad * 8;
            s16x8 bv0 = *(const s16x8*)(vp);
            s16x8 bv1 = *(const s16x8*)(vp + 32);
            o[nt] = __builtin_amdgcn_mfma_f32_16x16x32_bf16(ap0, bv0, o[nt], 0, 0, 0);
            o[nt] = __builtin_amdgcn_mfma_f32_16x16x32_bf16(ap1, bv1, o[nt], 0, 0, 0);
        }
    }

    // ---- per-wave: reduce row sums across the 16 col-lanes ----
#pragma unroll
    for (int r = 0; r < 4; ++r) {
        float v = lsum[r];
        v += __shfl_xor(v, 1, 64);
        v += __shfl_xor(v, 2, 64);
        v += __shfl_xor(v, 4, 64);
        v += __shfl_xor(v, 8, 64);
        lsum[r] = v;
    }

    // ---- combine the 4 key-splits in LDS ----
    if (sp > 0) {
        float* ox = &Ox[(sp - 1) * 4 + qg][0];
#pragma unroll
        for (int nt = 0; nt < 4; ++nt)
#pragma unroll
            for (int r = 0; r < 4; ++r)
                ox[(quad * 4 + r) * OX_STRIDE + nt * 16 + col] = o[nt][r];
        if (col == 0) {
#pragma unroll
            for (int r = 0; r < 4; ++r)
                Lx[((sp - 1) * 4 + qg) * 16 + quad * 4 + r] = lsum[r];
        }
    }
    __syncthreads();
    if (sp == 0) {
        float linv[4];
#pragma unroll
        for (int r = 0; r < 4; ++r) {
            float l = lsum[r];
#pragma unroll
            for (int s = 0; s < 3; ++s)
                l += Lx[(s * 4 + qg) * 16 + quad * 4 + r];
            linv[r] = 1.0f / l;
        }
#pragma unroll
        for (int s = 0; s < 3; ++s) {
            const float* ox = &Ox[s * 4 + qg][0];
#pragma unroll
            for (int nt = 0; nt < 4; ++nt)
#pragma unroll
                for (int r = 0; r < 4; ++r)
                    o[nt][r] += ox[(quad * 4 + r) * OX_STRIDE + nt * 16 + col];
        }
        const float g = gamma[0];
#pragma unroll
        for (int nt = 0; nt < 4; ++nt) {
            const int c = nt * 16 + col;
#pragma unroll
            for (int r = 0; r < 4; ++r) {
                const int i = iw + quad * 4 + r;
                const size_t idx = ((size_t)(b * 64 + c)) * 4096 + i;
                out[idx] = g * (o[nt][r] * linv[r]) + x[idx];
            }
        }
    }
}

// ---------------------------------------------------------------------------
extern "C" void kernel_launch(void* const* d_in, const int* in_sizes, int n_in,
                              void* d_out, int out_size, void* d_ws, size_t ws_size,
                              hipStream_t stream)
{
    const float* x     = (const float*)d_in[0];
    const float* Wq    = (const float*)d_in[1];
    const float* bq    = (const float*)d_in[2];
    const float* Wk    = (const float*)d_in[3];
    const float* bk    = (const float*)d_in[4];
    const float* Wv    = (const float*)d_in[5];
    const float* bv    = (const float*)d_in[6];
    const float* gamma = (const float*)d_in[7];

    u16* QT = (u16*)d_ws;                 // [4][4096][8] bf16
    u16* KT = QT + (size_t)4 * 4096 * 8;  // [4][4096][8] bf16
    u16* Vg = KT + (size_t)4 * 4096 * 8;  // [4][64][4096] bf16

    qkv_kernel<<<1024, 256, 0, stream>>>(x, Wq, bq, Wk, bk, Wv, bv, QT, KT, Vg);
    attn_kernel<<<256, 1024, 0, stream>>>(QT, KT, Vg, x, gamma, (float*)d_out);
}